// Round 1
// baseline (180.788 us; speedup 1.0000x reference)
//
#include <hip/hip_runtime.h>

// Capsule routing on MI355X.
// Key algebraic identity: softmax over the capsule axis followed by a sum over
// that same axis is identically 1, so the dynamic-routing loop is dead code and
//   out[b, o] = sum_i ( sum_t x[b,t,i] ) * W[i, o]
// This reduces the problem to a column-sum over T (streams x once, 256 MB)
// plus a tiny (32 x 1024) @ (1024 x 2048) matmul.

#define BATCH   32
#define TLEN    2048
#define DIN     1024
#define DOUT    2048   // NUM_CAPSULE * DIM_CAPSULE
#define NCHUNK  32
#define ROWS_PER_CHUNK (TLEN / NCHUNK)  // 64

// ---------------------------------------------------------------------------
// Kernel 1: partial column sums of x over T.
// grid = (NCHUNK, BATCH), block = 256 threads; thread tx owns cols 4*tx..4*tx+3.
// Each block streams 64 rows (256 KB) of one batch; fully coalesced float4.
// ---------------------------------------------------------------------------
__global__ __launch_bounds__(256) void colsum_partial(
    const float* __restrict__ x, float* __restrict__ part)
{
    const int chunk = blockIdx.x;
    const int b     = blockIdx.y;
    const int tx    = threadIdx.x;

    const float4* base = reinterpret_cast<const float4*>(
        x + (size_t)b * TLEN * DIN + (size_t)chunk * ROWS_PER_CHUNK * DIN) + tx;

    float4 acc = make_float4(0.f, 0.f, 0.f, 0.f);
#pragma unroll 8
    for (int r = 0; r < ROWS_PER_CHUNK; ++r) {
        float4 v = base[r * (DIN / 4)];
        acc.x += v.x; acc.y += v.y; acc.z += v.z; acc.w += v.w;
    }
    float4* p = reinterpret_cast<float4*>(
        part + ((size_t)chunk * BATCH + b) * DIN) + tx;
    *p = acc;
}

// ---------------------------------------------------------------------------
// Kernel 2: reduce the NCHUNK partials into xs[b][i] (in LDS), then compute
//   out[b, o] = sum_i xs[b][i] * W[i, o]
// grid = (DOUT/256 = 8 col-chunks, BATCH/4 = 8 batch-groups), block = 256.
// xs reads inside the i-loop are wave-uniform (broadcast, no bank conflicts);
// W reads are coalesced across lanes.
// ---------------------------------------------------------------------------
#define BG 4     // batches per block
#define CC 256   // output cols per block

__global__ __launch_bounds__(256) void reduce_matmul(
    const float* __restrict__ part, const float* __restrict__ W,
    float* __restrict__ out)
{
    __shared__ float xs[BG][DIN];   // 16 KB

    const int cb = blockIdx.x;   // col chunk
    const int bg = blockIdx.y;   // batch group
    const int tx = threadIdx.x;

    // Reduce partials for this batch group into LDS.
    for (int bb = 0; bb < BG; ++bb) {
        const int b = bg * BG + bb;
        float4 acc = make_float4(0.f, 0.f, 0.f, 0.f);
#pragma unroll 8
        for (int c = 0; c < NCHUNK; ++c) {
            float4 v = reinterpret_cast<const float4*>(
                part + ((size_t)c * BATCH + b) * DIN)[tx];
            acc.x += v.x; acc.y += v.y; acc.z += v.z; acc.w += v.w;
        }
        reinterpret_cast<float4*>(&xs[bb][0])[tx] = acc;
    }
    __syncthreads();

    const int o = cb * CC + tx;
    float acc[BG] = {0.f, 0.f, 0.f, 0.f};
#pragma unroll 4
    for (int i = 0; i < DIN; ++i) {
        const float w = W[(size_t)i * DOUT + o];
#pragma unroll
        for (int bb = 0; bb < BG; ++bb) acc[bb] += xs[bb][i] * w;
    }
#pragma unroll
    for (int bb = 0; bb < BG; ++bb) {
        out[(size_t)(bg * BG + bb) * DOUT + o] = acc[bb];
    }
}

extern "C" void kernel_launch(void* const* d_in, const int* in_sizes, int n_in,
                              void* d_out, int out_size, void* d_ws, size_t ws_size,
                              hipStream_t stream)
{
    const float* x = (const float*)d_in[0];   // (32, 2048, 1024) f32
    const float* W = (const float*)d_in[1];   // (1024, 2048) f32
    float* out = (float*)d_out;               // (32, 32, 64) f32 flat
    float* part = (float*)d_ws;               // NCHUNK*BATCH*DIN f32 = 4 MB

    dim3 g1(NCHUNK, BATCH);
    colsum_partial<<<g1, 256, 0, stream>>>(x, part);

    dim3 g2(DOUT / CC, BATCH / BG);
    reduce_matmul<<<g2, 256, 0, stream>>>(part, W, out);
}

// Round 2
// 75.294 us; speedup vs baseline: 2.4011x; 2.4011x over previous
//
#include <hip/hip_runtime.h>

// Capsule routing on MI355X.
// Identity: softmax over the capsule axis followed by a sum over that axis is
// identically 1 -> the dynamic-routing loop is dead code and
//   out[b, o] = sum_i ( sum_t x[b,t,i] ) * W[i, o]
// => column-sum over T (streams x once, 256 MB, HBM-bound) + tiny matmul.
//
// Three kernels:
//   K1 colsum_partial : x (32,2048,1024) -> part (64 chunks, 32 b, 1024 i)  ~45 us
//   K2 chunk_reduce   : part -> xs (32,1024)                                ~2 us
//   K3 matmul_small   : xs @ W -> out (32,2048)                             ~5 us

#define BATCH   32
#define TLEN    2048
#define DIN     1024
#define DOUT    2048            // NUM_CAPSULE * DIM_CAPSULE
#define NCHUNK  64
#define RPC     (TLEN / NCHUNK) // 32 rows per chunk

// ---------------------------------------------------------------------------
// K1: partial column sums of x over T.
// grid = (NCHUNK, BATCH) = 2048 blocks, 256 threads -> 32 waves/CU (max occ).
// Thread tx owns float4 column tx; each block streams 32 rows (128 KB).
// ---------------------------------------------------------------------------
__global__ __launch_bounds__(256) void colsum_partial(
    const float* __restrict__ x, float* __restrict__ part)
{
    const int chunk = blockIdx.x;
    const int b     = blockIdx.y;
    const int tx    = threadIdx.x;

    const float4* base = reinterpret_cast<const float4*>(
        x + (size_t)b * TLEN * DIN + (size_t)chunk * RPC * DIN) + tx;

    float4 a0 = make_float4(0.f, 0.f, 0.f, 0.f);
    float4 a1 = make_float4(0.f, 0.f, 0.f, 0.f);
#pragma unroll 8
    for (int r = 0; r < RPC; r += 2) {
        float4 v0 = base[(size_t)r       * (DIN / 4)];
        float4 v1 = base[(size_t)(r + 1) * (DIN / 4)];
        a0.x += v0.x; a0.y += v0.y; a0.z += v0.z; a0.w += v0.w;
        a1.x += v1.x; a1.y += v1.y; a1.z += v1.z; a1.w += v1.w;
    }
    a0.x += a1.x; a0.y += a1.y; a0.z += a1.z; a0.w += a1.w;

    reinterpret_cast<float4*>(part + ((size_t)chunk * BATCH + b) * DIN)[tx] = a0;
}

// ---------------------------------------------------------------------------
// K2: reduce NCHUNK partials -> xs[b][i].
// grid = BATCH blocks of 256 threads; thread tx owns float4 column tx of batch b.
// ---------------------------------------------------------------------------
__global__ __launch_bounds__(256) void chunk_reduce(
    const float* __restrict__ part, float* __restrict__ xs)
{
    const int b  = blockIdx.x;
    const int tx = threadIdx.x;

    float4 acc = make_float4(0.f, 0.f, 0.f, 0.f);
#pragma unroll 8
    for (int c = 0; c < NCHUNK; ++c) {
        float4 v = reinterpret_cast<const float4*>(
            part + ((size_t)c * BATCH + b) * DIN)[tx];
        acc.x += v.x; acc.y += v.y; acc.z += v.z; acc.w += v.w;
    }
    reinterpret_cast<float4*>(xs + (size_t)b * DIN)[tx] = acc;
}

// ---------------------------------------------------------------------------
// K3: out[b, o] = sum_i xs[b][i] * W[i, o]
// grid = (DOUT/CB = 16, BATCH/BG = 8) = 128 blocks, 1024 threads (16 waves).
// Thread (ol = tx&127, iq = tx>>7) accumulates cols o=cb*128+ol over the
// i-segment [iq*128, iq*128+128) for BG=4 batches -> chain length 128,
// 4 waves/SIMD for latency hiding. xs reads are wave-uniform (L1-hot).
// 8-way partial reduce through 16 KB LDS.
// ---------------------------------------------------------------------------
#define CB 128  // output cols per block
#define BG 4    // batches per block
#define IQ 8    // i-segments per block

__global__ __launch_bounds__(1024) void matmul_small(
    const float* __restrict__ xs, const float* __restrict__ W,
    float* __restrict__ out)
{
    __shared__ float ps[IQ][BG][CB];  // 16 KB

    const int cb = blockIdx.x;
    const int bg = blockIdx.y;
    const int tx = threadIdx.x;
    const int ol = tx & (CB - 1);
    const int iq = tx >> 7;
    const int o  = cb * CB + ol;
    const int i0 = iq * (DIN / IQ);

    const float* wp = W + (size_t)i0 * DOUT + o;
    const float* x0 = xs + (size_t)(bg * BG + 0) * DIN + i0;
    const float* x1 = xs + (size_t)(bg * BG + 1) * DIN + i0;
    const float* x2 = xs + (size_t)(bg * BG + 2) * DIN + i0;
    const float* x3 = xs + (size_t)(bg * BG + 3) * DIN + i0;

    float acc0 = 0.f, acc1 = 0.f, acc2 = 0.f, acc3 = 0.f;
#pragma unroll 8
    for (int k = 0; k < DIN / IQ; ++k) {
        const float w = wp[(size_t)k * DOUT];
        acc0 += x0[k] * w;
        acc1 += x1[k] * w;
        acc2 += x2[k] * w;
        acc3 += x3[k] * w;
    }
    ps[iq][0][ol] = acc0;
    ps[iq][1][ol] = acc1;
    ps[iq][2][ol] = acc2;
    ps[iq][3][ol] = acc3;
    __syncthreads();

    if (tx < BG * CB) {           // 512 threads write the block's outputs
        const int ol2 = tx & (CB - 1);
        const int bb  = tx >> 7;  // 0..3
        float s = 0.f;
#pragma unroll
        for (int q = 0; q < IQ; ++q) s += ps[q][bb][ol2];
        out[(size_t)(bg * BG + bb) * DOUT + cb * CB + ol2] = s;
    }
}

extern "C" void kernel_launch(void* const* d_in, const int* in_sizes, int n_in,
                              void* d_out, int out_size, void* d_ws, size_t ws_size,
                              hipStream_t stream)
{
    const float* x = (const float*)d_in[0];   // (32, 2048, 1024) f32
    const float* W = (const float*)d_in[1];   // (1024, 2048) f32
    float* out  = (float*)d_out;              // (32, 32, 64) f32 flat
    float* part = (float*)d_ws;                               // 8 MB
    float* xs   = (float*)d_ws + (size_t)NCHUNK * BATCH * DIN; // 128 KB

    dim3 g1(NCHUNK, BATCH);
    colsum_partial<<<g1, 256, 0, stream>>>(x, part);

    chunk_reduce<<<BATCH, 256, 0, stream>>>(part, xs);

    dim3 g3(DOUT / CB, BATCH / BG);
    matmul_small<<<g3, 1024, 0, stream>>>(xs, W, out);
}